// Round 2
// baseline (252.739 us; speedup 1.0000x reference)
//
#include <hip/hip_runtime.h>

// GCN 2-layer forward. R12 = R11 (direct-atomic padded-CSR build) with the
// workspace shrunk back under the last-passing footprint: R11 grew ws by
// +398KB (cnt[N] replacing 2KB bcur) and died with a host abort -- most
// plausible cause is ovf hanging past ws_size. OVF_MAX 65536->4096 (expected
// spills ~0.01 edges; Poisson(12) tail past CAP=32) makes the new layout
// strictly smaller than the known-good one. Build = one pass: atomicAdd
// per-node counter (400KB, L2-resident) + scattered 4B adj write. dinv folded
// into gemm1. Gather kernels byte-identical to the 178us version: 8
// lanes/node, bf16 message rows (64B), fp32 accumulate, mid fused into
// gather-1, gemm2 fused into gather-2.

#define CAP 32
#define OVF_MAX 4096

__device__ __forceinline__ unsigned bf16rn(float f) {
    unsigned u = __float_as_uint(f);
    return (u + 0x7fffu + ((u >> 16) & 1u)) >> 16;   // round-to-nearest-even
}
__device__ __forceinline__ unsigned pack2(float f0, float f1) {
    return (bf16rn(f1) << 16) | bf16rn(f0);
}
__device__ __forceinline__ void acc2(float4& a, uint2 v) {
    a.x += __uint_as_float(v.x << 16);
    a.y += __uint_as_float(v.x & 0xffff0000u);
    a.z += __uint_as_float(v.y << 16);
    a.w += __uint_as_float(v.y & 0xffff0000u);
}

// Sentinel-fill adj (slot==N -> zeroed message row), zero counters and the
// two sentinel rows. Grid covers 8N int4 slots (12.8 MB, streaming).
__global__ __launch_bounds__(256) void init_kernel(int4* __restrict__ adj4,
                                                   int* __restrict__ cnt,
                                                   int* __restrict__ ovfcnt,
                                                   unsigned int* __restrict__ g1rowN,
                                                   unsigned int* __restrict__ q1rowN, int N) {
    int i = blockIdx.x * blockDim.x + threadIdx.x;
    int NA = 8 * N;                       // int4 slots in adj
    if (i < NA) adj4[i] = make_int4(N, N, N, N);
    if (i < N) cnt[i] = 0;
    if (i == 0) *ovfcnt = 0;
    if (i < 16) { g1rowN[i] = 0u; q1rowN[i] = 0u; }   // bf16 zero rows
}

// One thread per edge: reserve a slot in dst's padded row via global atomic
// (counter array 400 KB -> L2-resident, ~12-way avg same-address reuse),
// write src id. Slots fill densely from 0, so the gather's slot-16 sentinel
// test stays valid. deg>CAP spills to the exact overflow list (~0.01 edges
// expected total).
__global__ __launch_bounds__(256) void build_kernel(const int* __restrict__ src,
                                                    const int* __restrict__ dst,
                                                    int* __restrict__ cnt,
                                                    int* __restrict__ adj,
                                                    int* __restrict__ ovfcnt,
                                                    int* __restrict__ ovf, int E, int N) {
    int e = blockIdx.x * blockDim.x + threadIdx.x;
    if (e < E) {
        int s = src[e], d = dst[e];
        if ((unsigned)d < (unsigned)N && (unsigned)s < (unsigned)N) {  // fault guard
            int q = atomicAdd(&cnt[d], 1);    // counts ALL edges -> dinv exact
            if (q < CAP) adj[(size_t)d * CAP + q] = s;
            else {
                int o = atomicAdd(ovfcnt, 1);
                if (o < OVF_MAX) { ovf[2 * o] = s; ovf[2 * o + 1] = d; }
            }
        }
    }
}

// g1 = bf16( dinv * (x @ W1) ), dinv computed here from cnt (fused). Block =
// 16 nodes x 16 lanes; each lane computes feature pair (2j, 2j+1) -> one
// packed uint. Row = 16 uints = 64B.
__global__ __launch_bounds__(256) void gemm1_kernel(const float* __restrict__ x,
                                                    const float* __restrict__ W1,
                                                    const int* __restrict__ cnt,
                                                    float* __restrict__ dinv,
                                                    unsigned int* __restrict__ g1, int N) {
    __shared__ float Ws[64 * 32];
    __shared__ float xs[16][64];
    int tid = threadIdx.x;
    const float4* W4 = (const float4*)W1;
    float4* Ws4 = (float4*)Ws;
    for (int i = tid; i < 512; i += 256) Ws4[i] = W4[i];
    int nb = blockIdx.x * 16;
    {
        int ln = tid >> 4, k4 = (tid & 15) * 4;
        int n = nb + ln;
        float4 v = make_float4(0.f, 0.f, 0.f, 0.f);
        if (n < N) v = *(const float4*)(x + (size_t)n * 64 + k4);
        *(float4*)(&xs[ln][k4]) = v;
    }
    __syncthreads();
    int ln = tid >> 4, j = tid & 15;
    int n = nb + ln;
    if (n < N) {
        float s0 = 0.f, s1 = 0.f;
#pragma unroll
        for (int k = 0; k < 64; ++k) {
            float xv = xs[ln][k];
            s0 += xv * Ws[k * 32 + 2 * j];
            s1 += xv * Ws[k * 32 + 2 * j + 1];
        }
        float dv = rsqrtf((float)cnt[n] + 1.0f);   // +1 = self-loop
        if (j == 0) dinv[n] = dv;
        g1[(size_t)n * 16 + j] = pack2(dv * s0, dv * s1);
    }
}

// 8 lanes per node: lane l holds features 4l..4l+3 (uint2 of bf16x2) and
// neighbor slots 4l..4l+3 (int4). One VMEM inst fetches 8 rows (512B).
// Pad slots hold N -> zeroed row; slots 16..31 gated per-octet by exec mask.
__device__ __forceinline__ float4 gather_row4(const int4* __restrict__ adj4,
                                              const int* __restrict__ ovfcnt,
                                              const int* __restrict__ ovf,
                                              const uint2* __restrict__ g2,
                                              int n, int l, int N) {
    int4 idx = adj4[(size_t)n * 8 + l];
    float4 a = make_float4(0.f, 0.f, 0.f, 0.f);
    uint2 self = g2[(size_t)n * 8 + l];
    {
        int s0  = __shfl(idx.x, 0, 8), s1  = __shfl(idx.y, 0, 8);
        int s2  = __shfl(idx.z, 0, 8), s3  = __shfl(idx.w, 0, 8);
        int s4  = __shfl(idx.x, 1, 8), s5  = __shfl(idx.y, 1, 8);
        int s6  = __shfl(idx.z, 1, 8), s7  = __shfl(idx.w, 1, 8);
        int s8  = __shfl(idx.x, 2, 8), s9  = __shfl(idx.y, 2, 8);
        int s10 = __shfl(idx.z, 2, 8), s11 = __shfl(idx.w, 2, 8);
        int s12 = __shfl(idx.x, 3, 8), s13 = __shfl(idx.y, 3, 8);
        int s14 = __shfl(idx.z, 3, 8), s15 = __shfl(idx.w, 3, 8);
        uint2 v0  = g2[(size_t)s0  * 8 + l], v1  = g2[(size_t)s1  * 8 + l];
        uint2 v2  = g2[(size_t)s2  * 8 + l], v3  = g2[(size_t)s3  * 8 + l];
        uint2 v4  = g2[(size_t)s4  * 8 + l], v5  = g2[(size_t)s5  * 8 + l];
        uint2 v6  = g2[(size_t)s6  * 8 + l], v7  = g2[(size_t)s7  * 8 + l];
        uint2 v8  = g2[(size_t)s8  * 8 + l], v9  = g2[(size_t)s9  * 8 + l];
        uint2 v10 = g2[(size_t)s10 * 8 + l], v11 = g2[(size_t)s11 * 8 + l];
        uint2 v12 = g2[(size_t)s12 * 8 + l], v13 = g2[(size_t)s13 * 8 + l];
        uint2 v14 = g2[(size_t)s14 * 8 + l], v15 = g2[(size_t)s15 * 8 + l];
        acc2(a, self);
        acc2(a, v0);  acc2(a, v1);  acc2(a, v2);  acc2(a, v3);
        acc2(a, v4);  acc2(a, v5);  acc2(a, v6);  acc2(a, v7);
        acc2(a, v8);  acc2(a, v9);  acc2(a, v10); acc2(a, v11);
        acc2(a, v12); acc2(a, v13); acc2(a, v14); acc2(a, v15);
    }
    if (__shfl(idx.x, 4, 8) != N) {        // neighbors beyond 16?
        int s0  = __shfl(idx.x, 4, 8), s1  = __shfl(idx.y, 4, 8);
        int s2  = __shfl(idx.z, 4, 8), s3  = __shfl(idx.w, 4, 8);
        int s4  = __shfl(idx.x, 5, 8), s5  = __shfl(idx.y, 5, 8);
        int s6  = __shfl(idx.z, 5, 8), s7  = __shfl(idx.w, 5, 8);
        int s8  = __shfl(idx.x, 6, 8), s9  = __shfl(idx.y, 6, 8);
        int s10 = __shfl(idx.z, 6, 8), s11 = __shfl(idx.w, 6, 8);
        int s12 = __shfl(idx.x, 7, 8), s13 = __shfl(idx.y, 7, 8);
        int s14 = __shfl(idx.z, 7, 8), s15 = __shfl(idx.w, 7, 8);
        uint2 v0  = g2[(size_t)s0  * 8 + l], v1  = g2[(size_t)s1  * 8 + l];
        uint2 v2  = g2[(size_t)s2  * 8 + l], v3  = g2[(size_t)s3  * 8 + l];
        uint2 v4  = g2[(size_t)s4  * 8 + l], v5  = g2[(size_t)s5  * 8 + l];
        uint2 v6  = g2[(size_t)s6  * 8 + l], v7  = g2[(size_t)s7  * 8 + l];
        uint2 v8  = g2[(size_t)s8  * 8 + l], v9  = g2[(size_t)s9  * 8 + l];
        uint2 v10 = g2[(size_t)s10 * 8 + l], v11 = g2[(size_t)s11 * 8 + l];
        uint2 v12 = g2[(size_t)s12 * 8 + l], v13 = g2[(size_t)s13 * 8 + l];
        uint2 v14 = g2[(size_t)s14 * 8 + l], v15 = g2[(size_t)s15 * 8 + l];
        acc2(a, v0);  acc2(a, v1);  acc2(a, v2);  acc2(a, v3);
        acc2(a, v4);  acc2(a, v5);  acc2(a, v6);  acc2(a, v7);
        acc2(a, v8);  acc2(a, v9);  acc2(a, v10); acc2(a, v11);
        acc2(a, v12); acc2(a, v13); acc2(a, v14); acc2(a, v15);
    }
    int c = *ovfcnt; if (c > OVF_MAX) c = OVF_MAX;   // ~always 0
    for (int i = 0; i < c; ++i) {
        if (ovf[2 * i + 1] == n) acc2(a, g2[(size_t)ovf[2 * i] * 8 + l]);
    }
    return a;
}

// Layer-1 aggregate + fused mid: q = bf16( dinv * relu(dinv*agg + b1) ).
__global__ void gather_q_kernel(const int4* __restrict__ adj4,
                                const int* __restrict__ ovfcnt, const int* __restrict__ ovf,
                                const uint2* __restrict__ g2, const float* __restrict__ dinv,
                                const float* __restrict__ b1, uint2* __restrict__ q2, int N) {
    int tid = blockIdx.x * blockDim.x + threadIdx.x;
    int n = tid >> 3, l = tid & 7;
    if (n < N) {
        float4 a = gather_row4(adj4, ovfcnt, ovf, g2, n, l, N);
        float dv = dinv[n];
        float4 bb = ((const float4*)b1)[l];
        float vx = dv * a.x + bb.x, vy = dv * a.y + bb.y;
        float vz = dv * a.z + bb.z, vw = dv * a.w + bb.w;
        vx = vx > 0.f ? vx : 0.f; vy = vy > 0.f ? vy : 0.f;
        vz = vz > 0.f ? vz : 0.f; vw = vw > 0.f ? vw : 0.f;
        q2[(size_t)n * 8 + l] = make_uint2(pack2(dv * vx, dv * vy), pack2(dv * vz, dv * vw));
    }
}

// Layer-2 aggregate + fused gemm2: out[n,:] = dinv[n]*(agg2[n,:] @ W2) + b2.
// Block = 256 thr = 32 nodes (8 lanes each); agg staged in LDS (fp32).
__global__ __launch_bounds__(256) void gather_out_kernel(
        const int4* __restrict__ adj4,
        const int* __restrict__ ovfcnt, const int* __restrict__ ovf,
        const uint2* __restrict__ q2, const float* __restrict__ dinv,
        const float* __restrict__ W2, const float* __restrict__ b2,
        float* __restrict__ out, int N) {
    __shared__ float Ws[32 * 64];
    __shared__ float sAgg[32][36];     // stride 36: float4-aligned, conflict-free
    int tid = threadIdx.x;
    const float4* W4 = (const float4*)W2;
    float4* Ws4 = (float4*)Ws;
    for (int i = tid; i < 512; i += 256) Ws4[i] = W4[i];
    int nb = blockIdx.x * 32;
    int o = tid >> 3, l = tid & 7;
    int n = nb + o;
    if (n < N) *(float4*)(&sAgg[o][l * 4]) = gather_row4(adj4, ovfcnt, ovf, q2, n, l, N);
    __syncthreads();
    int ln = tid >> 6, j = tid & 63;   // 4 waves x 64 feats
#pragma unroll
    for (int nn = 0; nn < 8; ++nn) {
        int ol = nn * 4 + ln;
        int node = nb + ol;
        if (node < N) {
            float s = 0.f;
#pragma unroll
            for (int k = 0; k < 32; ++k) s += sAgg[ol][k] * Ws[k * 64 + j];
            out[(size_t)node * 64 + j] = dinv[node] * s + b2[j];
        }
    }
}

extern "C" void kernel_launch(void* const* d_in, const int* in_sizes, int n_in,
                              void* d_out, int out_size, void* d_ws, size_t ws_size,
                              hipStream_t stream) {
    const float* x  = (const float*)d_in[0];
    const int*   ei = (const int*)d_in[1];   // int32, shape (2,E) flat
    const float* W1 = (const float*)d_in[2];
    const float* b1 = (const float*)d_in[3];
    const float* W2 = (const float*)d_in[4];
    const float* b2 = (const float*)d_in[5];
    float* out = (float*)d_out;

    int N = in_sizes[0] / 64;        // 100000
    int E = in_sizes[1] / 2;         // 1200000
    const int* src = ei;
    const int* dst = ei + (size_t)E;

    // ws: dinv[N] f | g1[16(N+1)] u32 (bf16 rows) | q1[16(N+1)] u32 |
    // adj[32N] i | cnt[N] i | ovfcnt[4] i | ovf[2*OVF_MAX] i
    // total 26,432,912 B -- strictly under the last-passing 26,526,480 B.
    size_t NP = (size_t)N + 1;
    float* dinv   = (float*)d_ws;
    unsigned int* g1 = (unsigned int*)(dinv + N);
    unsigned int* q1 = g1 + 16 * NP;
    int*   adj    = (int*)(q1 + 16 * NP);
    int*   cnt    = adj + (size_t)CAP * N;
    int*   ovfcnt = cnt + N;
    int*   ovf    = ovfcnt + 4;

    int NA = 8 * N;                  // int4 slots in adj
    init_kernel<<<(NA + 255) / 256, 256, 0, stream>>>(
        (int4*)adj, cnt, ovfcnt, g1 + 16 * (size_t)N, q1 + 16 * (size_t)N, N);
    build_kernel<<<(E + 255) / 256, 256, 0, stream>>>(src, dst, cnt, adj, ovfcnt, ovf, E, N);

    gemm1_kernel<<<(N + 15) / 16, 256, 0, stream>>>(x, W1, cnt, dinv, g1, N);

    long long tq = (long long)N * 8;
    gather_q_kernel<<<(int)((tq + 255) / 256), 256, 0, stream>>>(
        (const int4*)adj, ovfcnt, ovf, (const uint2*)g1, dinv, b1, (uint2*)q1, N);
    gather_out_kernel<<<(N + 31) / 32, 256, 0, stream>>>(
        (const int4*)adj, ovfcnt, ovf, (const uint2*)q1, dinv, W2, b2, out, N);
}

// Round 3
// 167.790 us; speedup vs baseline: 1.5063x; 1.5063x over previous
//
#include <hip/hip_runtime.h>

// GCN 2-layer forward. R13: (a) build reverted to the proven R0 bucketed
// bin/fillb (R2 measured the direct-atomic build at 95us: 1.2M scattered 4B
// writes -> 71.8MB of 64B-line writebacks at ~750GB/s; bucketed build keeps
// all global writes coalesced, ~25us). (b) gemm1 rewritten as MFMA
// 16x16x32_bf16 with hi/lo split of x and W1 (3-term product, fp32-accurate)
// and NO LDS: A-frags loaded dense from x (128B/node/kstep), B-frags from
// L1-hot W1. k-order inside fragments is chosen consistently for A and B
// (k = q*8+e), which is correct for any HW k-permutation since 16x16-family
// A/B frags share the same (group,elem)->k map. Gathers byte-identical:
// 8 lanes/node, bf16 message rows (64B), fp32 accumulate, mid fused into
// gather-1, gemm2 fused into gather-2.

#define CAP 32
#define OVF_MAX 65536
#define SH_BITS 8
#define SH 256          // nodes per bucket
#define BCAP 3584       // edge capacity per bucket (E/B ~ 3070, sigma ~ 55)
#define EPB 4096        // edges per bin block
#define EPT 16          // edges per thread in bin

typedef __attribute__((ext_vector_type(8))) short short8;
typedef __attribute__((ext_vector_type(4))) float f32x4;

__device__ __forceinline__ unsigned bf16rn(float f) {
    unsigned u = __float_as_uint(f);
    return (u + 0x7fffu + ((u >> 16) & 1u)) >> 16;   // round-to-nearest-even
}
__device__ __forceinline__ unsigned pack2(float f0, float f1) {
    return (bf16rn(f1) << 16) | bf16rn(f0);
}
__device__ __forceinline__ void acc2(float4& a, uint2 v) {
    a.x += __uint_as_float(v.x << 16);
    a.y += __uint_as_float(v.x & 0xffff0000u);
    a.z += __uint_as_float(v.y << 16);
    a.w += __uint_as_float(v.y & 0xffff0000u);
}

__global__ void init_kernel(int* __restrict__ bcur, int* __restrict__ ovfcnt,
                            unsigned int* __restrict__ g1rowN,
                            unsigned int* __restrict__ q1rowN, int B) {
    int i = blockIdx.x * blockDim.x + threadIdx.x;
    if (i < B) bcur[i] = i * BCAP;
    if (i == 0) *ovfcnt = 0;
    if (i < 16) { g1rowN[i] = 0u; q1rowN[i] = 0u; }   // sentinel zero-rows (bf16 0 == 0u)
}

// Bin edges into fixed-stride bucket runs, payload packed to 4B:
// (dst&255)<<24 | src. LDS histogram -> one cursor atomic per touched bucket
// -> packed writes at reserved base + block-local rank. Bucket-cap spill goes
// to the exact global overflow list (P ~ 1e-19).
__global__ __launch_bounds__(256) void bin_kernel(const int* __restrict__ src,
                                                  const int* __restrict__ dst,
                                                  int* __restrict__ bcur,
                                                  unsigned int* __restrict__ ebuf,
                                                  int* __restrict__ ovfcnt,
                                                  int* __restrict__ ovf, int E, int B) {
    __shared__ int h[512];
    __shared__ int gp[512];
    __shared__ int lr[512];
    for (int b = threadIdx.x; b < B; b += 256) { h[b] = 0; lr[b] = 0; }
    __syncthreads();
    int base = blockIdx.x * EPB;
    int s[EPT], d[EPT], bk[EPT];
#pragma unroll
    for (int k = 0; k < EPT; ++k) {
        int e = base + k * 256 + threadIdx.x;
        bool ok = e < E;
        s[k]  = ok ? src[e] : 0;
        d[k]  = ok ? dst[e] : 0;
        bk[k] = ok ? (d[k] >> SH_BITS) : -1;
        if (ok) atomicAdd(&h[bk[k]], 1);
    }
    __syncthreads();
    for (int b = threadIdx.x; b < B; b += 256)
        if (h[b]) gp[b] = atomicAdd(&bcur[b], h[b]);
    __syncthreads();
#pragma unroll
    for (int k = 0; k < EPT; ++k) {
        if (bk[k] >= 0) {
            int r = atomicAdd(&lr[bk[k]], 1);
            int pos = gp[bk[k]] + r;
            if (pos < (bk[k] + 1) * BCAP)
                ebuf[pos] = ((unsigned)(d[k] & (SH - 1)) << 24) | (unsigned)s[k];
            else { int o = atomicAdd(ovfcnt, 1); if (o < OVF_MAX) { ovf[2 * o] = s[k]; ovf[2 * o + 1] = d[k]; } }
        }
    }
}

// One block per bucket: build the 256-node padded-CSR window in LDS, pad
// unused slots with sentinel N (-> zeroed g row), stream out dense.
__global__ __launch_bounds__(256) void fillb_kernel(const unsigned int* __restrict__ ebuf,
                                                    const int* __restrict__ bcur,
                                                    int* __restrict__ adj,
                                                    float* __restrict__ dinv,
                                                    int* __restrict__ ovfcnt,
                                                    int* __restrict__ ovf, int N) {
    __shared__ int lcnt[SH];
    __shared__ int ladj[SH * CAP];     // 32 KB
    int b = blockIdx.x;
    for (int i = threadIdx.x; i < SH; i += 256) lcnt[i] = 0;
    for (int i = threadIdx.x; i < SH * CAP; i += 256) ladj[i] = N;   // sentinel pad
    __syncthreads();
    int beg = b * BCAP;
    int tot = bcur[b] - beg;
    int m = tot < BCAP ? tot : BCAP;
    for (int i = threadIdx.x; i < m; i += 256) {
        unsigned p = ebuf[beg + i];
        int ld = (int)(p >> 24), sidx = (int)(p & 0xFFFFFF);
        int q = atomicAdd(&lcnt[ld], 1);
        if (q < CAP) ladj[ld * CAP + q] = sidx;
        else { int o = atomicAdd(ovfcnt, 1); if (o < OVF_MAX) { ovf[2 * o] = sidx; ovf[2 * o + 1] = (b << SH_BITS) + ld; } }
    }
    __syncthreads();
    int nb0 = b << SH_BITS;
    const int4* l4 = (const int4*)ladj;
    int4* a4 = (int4*)(adj + (size_t)nb0 * CAP);
    for (int i = threadIdx.x; i < SH * CAP / 4; i += 256) {
        int nd = nb0 + (i * 4) / CAP;
        if (nd < N) a4[i] = l4[i];
    }
    for (int i = threadIdx.x; i < SH; i += 256) {
        int nd = nb0 + i;
        if (nd < N) dinv[nd] = rsqrtf((float)lcnt[i] + 1.0f);   // +1 = self-loop
    }
}

// g1 = bf16( dinv * (x @ W1) ) via MFMA. Block = 4 waves x 16-node tiles =
// 64 nodes. Per wave: A = x[16 nodes][64] hi/lo bf16 frags loaded straight
// from global (dense 128B per node per k-step), B = W1 hi/lo frags (L1-hot).
// 12 MFMA per wave. Fragment fill uses k = (lane>>4)*8 + e for BOTH A and B;
// consistency makes any HW k-permutation correct. C/D: col=lane&15,
// row=(lane>>4)*4+reg (verified map). No LDS.
__global__ __launch_bounds__(256) void gemm1_kernel(const float* __restrict__ x,
                                                    const float* __restrict__ W1,
                                                    const float* __restrict__ dinv,
                                                    unsigned int* __restrict__ g1, int N) {
    int wid = threadIdx.x >> 6;
    int lane = threadIdx.x & 63;
    int c = lane & 15, q = lane >> 4;
    int nb = blockIdx.x * 64 + wid * 16;

    // B fragments: W1 is [64][32] row-major; tile f covers feats f*16+c.
    short8 Bh[2][2], Bl[2][2];
#pragma unroll
    for (int f = 0; f < 2; ++f)
#pragma unroll
        for (int s = 0; s < 2; ++s) {
            short8 bh, bl;
#pragma unroll
            for (int e = 0; e < 8; ++e) {
                float w = W1[(size_t)(s * 32 + q * 8 + e) * 32 + f * 16 + c];
                unsigned hb = bf16rn(w);
                bh[e] = (short)hb;
                bl[e] = (short)bf16rn(w - __uint_as_float(hb << 16));
            }
            Bh[f][s] = bh; Bl[f][s] = bl;
        }

    int n_row = nb + c;
    bool rowok = n_row < N;
    f32x4 acc0 = {0.f, 0.f, 0.f, 0.f};
    f32x4 acc1 = {0.f, 0.f, 0.f, 0.f};
#pragma unroll
    for (int s = 0; s < 2; ++s) {
        float4 va = make_float4(0.f, 0.f, 0.f, 0.f);
        float4 vb = make_float4(0.f, 0.f, 0.f, 0.f);
        if (rowok) {
            const float* xr = x + (size_t)n_row * 64 + s * 32 + q * 8;
            va = *(const float4*)xr;
            vb = *(const float4*)(xr + 4);
        }
        float xv[8] = {va.x, va.y, va.z, va.w, vb.x, vb.y, vb.z, vb.w};
        short8 Ah, Al;
#pragma unroll
        for (int e = 0; e < 8; ++e) {
            unsigned hb = bf16rn(xv[e]);
            Ah[e] = (short)hb;
            Al[e] = (short)bf16rn(xv[e] - __uint_as_float(hb << 16));
        }
        // 3-term hi/lo product (lo*lo negligible): fp32-accurate gemm.
        acc0 = __builtin_amdgcn_mfma_f32_16x16x32_bf16(Ah, Bh[0][s], acc0, 0, 0, 0);
        acc0 = __builtin_amdgcn_mfma_f32_16x16x32_bf16(Al, Bh[0][s], acc0, 0, 0, 0);
        acc0 = __builtin_amdgcn_mfma_f32_16x16x32_bf16(Ah, Bl[0][s], acc0, 0, 0, 0);
        acc1 = __builtin_amdgcn_mfma_f32_16x16x32_bf16(Ah, Bh[1][s], acc1, 0, 0, 0);
        acc1 = __builtin_amdgcn_mfma_f32_16x16x32_bf16(Al, Bh[1][s], acc1, 0, 0, 0);
        acc1 = __builtin_amdgcn_mfma_f32_16x16x32_bf16(Ah, Bl[1][s], acc1, 0, 0, 0);
    }

    // Epilogue: row(node) = nb + q*4 + reg, col(feat) = f*16 + c. Pair the
    // even/odd feat lanes via shfl_xor(1) and pack to one u32 per pair.
#pragma unroll
    for (int reg = 0; reg < 4; ++reg) {
        int n = nb + q * 4 + reg;
        if (n < N) {
            float dv = dinv[n];
            float v0 = acc0[reg] * dv;
            float p0 = __shfl_xor(v0, 1);
            float v1 = acc1[reg] * dv;
            float p1 = __shfl_xor(v1, 1);
            if (!(c & 1)) {
                g1[(size_t)n * 16 + (c >> 1)]     = pack2(v0, p0);
                g1[(size_t)n * 16 + 8 + (c >> 1)] = pack2(v1, p1);
            }
        }
    }
}

// 8 lanes per node: lane l holds features 4l..4l+3 (uint2 of bf16x2) and
// neighbor slots 4l..4l+3 (int4). One VMEM inst fetches 8 rows (512B).
// Pad slots hold N -> zeroed row; slots 16..31 gated per-octet by exec mask.
__device__ __forceinline__ float4 gather_row4(const int4* __restrict__ adj4,
                                              const int* __restrict__ ovfcnt,
                                              const int* __restrict__ ovf,
                                              const uint2* __restrict__ g2,
                                              int n, int l, int N) {
    int4 idx = adj4[(size_t)n * 8 + l];
    float4 a = make_float4(0.f, 0.f, 0.f, 0.f);
    uint2 self = g2[(size_t)n * 8 + l];
    {
        int s0  = __shfl(idx.x, 0, 8), s1  = __shfl(idx.y, 0, 8);
        int s2  = __shfl(idx.z, 0, 8), s3  = __shfl(idx.w, 0, 8);
        int s4  = __shfl(idx.x, 1, 8), s5  = __shfl(idx.y, 1, 8);
        int s6  = __shfl(idx.z, 1, 8), s7  = __shfl(idx.w, 1, 8);
        int s8  = __shfl(idx.x, 2, 8), s9  = __shfl(idx.y, 2, 8);
        int s10 = __shfl(idx.z, 2, 8), s11 = __shfl(idx.w, 2, 8);
        int s12 = __shfl(idx.x, 3, 8), s13 = __shfl(idx.y, 3, 8);
        int s14 = __shfl(idx.z, 3, 8), s15 = __shfl(idx.w, 3, 8);
        uint2 v0  = g2[(size_t)s0  * 8 + l], v1  = g2[(size_t)s1  * 8 + l];
        uint2 v2  = g2[(size_t)s2  * 8 + l], v3  = g2[(size_t)s3  * 8 + l];
        uint2 v4  = g2[(size_t)s4  * 8 + l], v5  = g2[(size_t)s5  * 8 + l];
        uint2 v6  = g2[(size_t)s6  * 8 + l], v7  = g2[(size_t)s7  * 8 + l];
        uint2 v8  = g2[(size_t)s8  * 8 + l], v9  = g2[(size_t)s9  * 8 + l];
        uint2 v10 = g2[(size_t)s10 * 8 + l], v11 = g2[(size_t)s11 * 8 + l];
        uint2 v12 = g2[(size_t)s12 * 8 + l], v13 = g2[(size_t)s13 * 8 + l];
        uint2 v14 = g2[(size_t)s14 * 8 + l], v15 = g2[(size_t)s15 * 8 + l];
        acc2(a, self);
        acc2(a, v0);  acc2(a, v1);  acc2(a, v2);  acc2(a, v3);
        acc2(a, v4);  acc2(a, v5);  acc2(a, v6);  acc2(a, v7);
        acc2(a, v8);  acc2(a, v9);  acc2(a, v10); acc2(a, v11);
        acc2(a, v12); acc2(a, v13); acc2(a, v14); acc2(a, v15);
    }
    if (__shfl(idx.x, 4, 8) != N) {        // neighbors beyond 16?
        int s0  = __shfl(idx.x, 4, 8), s1  = __shfl(idx.y, 4, 8);
        int s2  = __shfl(idx.z, 4, 8), s3  = __shfl(idx.w, 4, 8);
        int s4  = __shfl(idx.x, 5, 8), s5  = __shfl(idx.y, 5, 8);
        int s6  = __shfl(idx.z, 5, 8), s7  = __shfl(idx.w, 5, 8);
        int s8  = __shfl(idx.x, 6, 8), s9  = __shfl(idx.y, 6, 8);
        int s10 = __shfl(idx.z, 6, 8), s11 = __shfl(idx.w, 6, 8);
        int s12 = __shfl(idx.x, 7, 8), s13 = __shfl(idx.y, 7, 8);
        int s14 = __shfl(idx.z, 7, 8), s15 = __shfl(idx.w, 7, 8);
        uint2 v0  = g2[(size_t)s0  * 8 + l], v1  = g2[(size_t)s1  * 8 + l];
        uint2 v2  = g2[(size_t)s2  * 8 + l], v3  = g2[(size_t)s3  * 8 + l];
        uint2 v4  = g2[(size_t)s4  * 8 + l], v5  = g2[(size_t)s5  * 8 + l];
        uint2 v6  = g2[(size_t)s6  * 8 + l], v7  = g2[(size_t)s7  * 8 + l];
        uint2 v8  = g2[(size_t)s8  * 8 + l], v9  = g2[(size_t)s9  * 8 + l];
        uint2 v10 = g2[(size_t)s10 * 8 + l], v11 = g2[(size_t)s11 * 8 + l];
        uint2 v12 = g2[(size_t)s12 * 8 + l], v13 = g2[(size_t)s13 * 8 + l];
        uint2 v14 = g2[(size_t)s14 * 8 + l], v15 = g2[(size_t)s15 * 8 + l];
        acc2(a, v0);  acc2(a, v1);  acc2(a, v2);  acc2(a, v3);
        acc2(a, v4);  acc2(a, v5);  acc2(a, v6);  acc2(a, v7);
        acc2(a, v8);  acc2(a, v9);  acc2(a, v10); acc2(a, v11);
        acc2(a, v12); acc2(a, v13); acc2(a, v14); acc2(a, v15);
    }
    int c = *ovfcnt; if (c > OVF_MAX) c = OVF_MAX;   // ~always 0
    for (int i = 0; i < c; ++i) {
        if (ovf[2 * i + 1] == n) acc2(a, g2[(size_t)ovf[2 * i] * 8 + l]);
    }
    return a;
}

// Layer-1 aggregate + fused mid: q = bf16( dinv * relu(dinv*agg + b1) ).
__global__ void gather_q_kernel(const int4* __restrict__ adj4,
                                const int* __restrict__ ovfcnt, const int* __restrict__ ovf,
                                const uint2* __restrict__ g2, const float* __restrict__ dinv,
                                const float* __restrict__ b1, uint2* __restrict__ q2, int N) {
    int tid = blockIdx.x * blockDim.x + threadIdx.x;
    int n = tid >> 3, l = tid & 7;
    if (n < N) {
        float4 a = gather_row4(adj4, ovfcnt, ovf, g2, n, l, N);
        float dv = dinv[n];
        float4 bb = ((const float4*)b1)[l];
        float vx = dv * a.x + bb.x, vy = dv * a.y + bb.y;
        float vz = dv * a.z + bb.z, vw = dv * a.w + bb.w;
        vx = vx > 0.f ? vx : 0.f; vy = vy > 0.f ? vy : 0.f;
        vz = vz > 0.f ? vz : 0.f; vw = vw > 0.f ? vw : 0.f;
        q2[(size_t)n * 8 + l] = make_uint2(pack2(dv * vx, dv * vy), pack2(dv * vz, dv * vw));
    }
}

// Layer-2 aggregate + fused gemm2: out[n,:] = dinv[n]*(agg2[n,:] @ W2) + b2.
// Block = 256 thr = 32 nodes (8 lanes each); agg staged in LDS (fp32).
__global__ __launch_bounds__(256) void gather_out_kernel(
        const int4* __restrict__ adj4,
        const int* __restrict__ ovfcnt, const int* __restrict__ ovf,
        const uint2* __restrict__ q2, const float* __restrict__ dinv,
        const float* __restrict__ W2, const float* __restrict__ b2,
        float* __restrict__ out, int N) {
    __shared__ float Ws[32 * 64];
    __shared__ float sAgg[32][36];     // stride 36: float4-aligned, conflict-free
    int tid = threadIdx.x;
    const float4* W4 = (const float4*)W2;
    float4* Ws4 = (float4*)Ws;
    for (int i = tid; i < 512; i += 256) Ws4[i] = W4[i];
    int nb = blockIdx.x * 32;
    int o = tid >> 3, l = tid & 7;
    int n = nb + o;
    if (n < N) *(float4*)(&sAgg[o][l * 4]) = gather_row4(adj4, ovfcnt, ovf, q2, n, l, N);
    __syncthreads();
    int ln = tid >> 6, j = tid & 63;   // 4 waves x 64 feats
#pragma unroll
    for (int nn = 0; nn < 8; ++nn) {
        int ol = nn * 4 + ln;
        int node = nb + ol;
        if (node < N) {
            float s = 0.f;
#pragma unroll
            for (int k = 0; k < 32; ++k) s += sAgg[ol][k] * Ws[k * 64 + j];
            out[(size_t)node * 64 + j] = dinv[node] * s + b2[j];
        }
    }
}

extern "C" void kernel_launch(void* const* d_in, const int* in_sizes, int n_in,
                              void* d_out, int out_size, void* d_ws, size_t ws_size,
                              hipStream_t stream) {
    const float* x  = (const float*)d_in[0];
    const int*   ei = (const int*)d_in[1];   // int32, shape (2,E) flat
    const float* W1 = (const float*)d_in[2];
    const float* b1 = (const float*)d_in[3];
    const float* W2 = (const float*)d_in[4];
    const float* b2 = (const float*)d_in[5];
    float* out = (float*)d_out;

    int N = in_sizes[0] / 64;        // 100000
    int E = in_sizes[1] / 2;         // 1200000
    const int* src = ei;
    const int* dst = ei + (size_t)E;
    int B = (N + SH - 1) >> SH_BITS; // 391 buckets

    // ws: dinv[N] f | g1[16(N+1)] u32 (bf16 rows) | q1[16(N+1)] u32 (aliases
    // ebuf[B*BCAP]=5.6MB < q1 6.4MB; ebuf dead before gather_q writes q1) |
    // adj[32N] i | bcur[512] i | ovfcnt[4] i | ovf[2*OVF_MAX] i   (~27 MB)
    size_t NP = (size_t)N + 1;
    float* dinv   = (float*)d_ws;
    unsigned int* g1 = (unsigned int*)(dinv + N);
    unsigned int* q1 = g1 + 16 * NP;
    unsigned int* ebuf = q1;
    int*   adj    = (int*)(q1 + 16 * NP);
    int*   bcur   = adj + (size_t)CAP * N;
    int*   ovfcnt = bcur + 512;
    int*   ovf    = ovfcnt + 4;

    init_kernel<<<(B + 255) / 256, 256, 0, stream>>>(bcur, ovfcnt,
                                                     g1 + 16 * (size_t)N, q1 + 16 * (size_t)N, B);
    bin_kernel<<<(E + EPB - 1) / EPB, 256, 0, stream>>>(src, dst, bcur, ebuf, ovfcnt, ovf, E, B);
    fillb_kernel<<<B, 256, 0, stream>>>(ebuf, bcur, adj, dinv, ovfcnt, ovf, N);

    gemm1_kernel<<<(N + 63) / 64, 256, 0, stream>>>(x, W1, dinv, g1, N);

    long long tq = (long long)N * 8;
    gather_q_kernel<<<(int)((tq + 255) / 256), 256, 0, stream>>>(
        (const int4*)adj, ovfcnt, ovf, (const uint2*)g1, dinv, b1, (uint2*)q1, N);
    gather_out_kernel<<<(N + 31) / 32, 256, 0, stream>>>(
        (const int4*)adj, ovfcnt, ovf, (const uint2*)q1, dinv, W2, b2, out, N);
}